// Round 1
// baseline (223.701 us; speedup 1.0000x reference)
//
#include <hip/hip_runtime.h>

// HarmonicMixing closed form per row of D=1024 channels:
//   out[j] = x[j]
//          + sum_{o=1..3, s=2^o} ( [j%s==0] * sig(uw[o]) * x[j/s]
//                                 + [1<=j<D/s] * sig(dw[o]) * sum_{k=j*s}^{(j+1)*s-1} x[k] )
// All gathers read the ORIGINAL x, so one pass with an LDS row buffer suffices.
// Memory-bound: 128 MB in + 128 MB out.

constexpr int D = 1024;

__global__ __launch_bounds__(256) void harmonic_kernel(
    const float* __restrict__ x,
    const float* __restrict__ uwp,
    const float* __restrict__ dwp,
    float* __restrict__ out)
{
    __shared__ float row[D];
    const int t = threadIdx.x;
    const long long base = (long long)blockIdx.x * D;

    // sigmoid(weights) — 6 scalar loads per block, broadcast
    const float uw0 = 1.f / (1.f + __expf(-uwp[0]));
    const float uw1 = 1.f / (1.f + __expf(-uwp[1]));
    const float uw2 = 1.f / (1.f + __expf(-uwp[2]));
    const float dw0 = 1.f / (1.f + __expf(-dwp[0]));
    const float dw1 = 1.f / (1.f + __expf(-dwp[1]));
    const float dw2 = 1.f / (1.f + __expf(-dwp[2]));

    const int j0 = t * 4;  // this thread's 4 consecutive channels
    const float4 v = *reinterpret_cast<const float4*>(x + base + j0);
    *reinterpret_cast<float4*>(&row[j0]) = v;
    __syncthreads();

    float4 r = v;

    // --- up contributions (gather from x[j/stride] when j % stride == 0) ---
    // j0 is a multiple of 4: j0, j0+2 are even; j0 is div by 4; j0 maybe div by 8.
    r.x += uw0 * row[j0 >> 1];
    r.z += uw0 * row[(j0 >> 1) + 1];
    r.x += uw1 * row[j0 >> 2];
    if ((j0 & 7) == 0) r.x += uw2 * row[j0 >> 3];

    // --- down contributions: out[j] += dw * sum(x[j*s .. j*s+s-1]), 1 <= j < D/s ---
    // stride 2, channels [1, 512)
    if (j0 < 512) {
        const float4 a = *reinterpret_cast<const float4*>(&row[2 * j0]);
        const float4 b = *reinterpret_cast<const float4*>(&row[2 * j0 + 4]);
        if (j0 > 0) r.x += dw0 * (a.x + a.y);
        r.y += dw0 * (a.z + a.w);
        r.z += dw0 * (b.x + b.y);
        r.w += dw0 * (b.z + b.w);
    }
    // stride 4, channels [1, 256)
    if (j0 < 256) {
        const float4 a = *reinterpret_cast<const float4*>(&row[4 * j0]);
        const float4 b = *reinterpret_cast<const float4*>(&row[4 * j0 + 4]);
        const float4 c = *reinterpret_cast<const float4*>(&row[4 * j0 + 8]);
        const float4 d = *reinterpret_cast<const float4*>(&row[4 * j0 + 12]);
        if (j0 > 0) r.x += dw1 * (a.x + a.y + a.z + a.w);
        r.y += dw1 * (b.x + b.y + b.z + b.w);
        r.z += dw1 * (c.x + c.y + c.z + c.w);
        r.w += dw1 * (d.x + d.y + d.z + d.w);
    }
    // stride 8, channels [1, 128)
    if (j0 < 128) {
        const float* p = &row[8 * j0];
        float s[4];
        #pragma unroll
        for (int k = 0; k < 4; ++k) {
            const float4 a = *reinterpret_cast<const float4*>(p + 8 * k);
            const float4 b = *reinterpret_cast<const float4*>(p + 8 * k + 4);
            s[k] = (a.x + a.y + a.z + a.w) + (b.x + b.y + b.z + b.w);
        }
        if (j0 > 0) r.x += dw2 * s[0];
        r.y += dw2 * s[1];
        r.z += dw2 * s[2];
        r.w += dw2 * s[3];
    }

    *reinterpret_cast<float4*>(out + base + j0) = r;
}

extern "C" void kernel_launch(void* const* d_in, const int* in_sizes, int n_in,
                              void* d_out, int out_size, void* d_ws, size_t ws_size,
                              hipStream_t stream) {
    const float* x   = (const float*)d_in[0];
    const float* uwp = (const float*)d_in[1];
    const float* dwp = (const float*)d_in[2];
    float* out = (float*)d_out;
    const int n_rows = in_sizes[0] / D;  // 8 * 4096 = 32768
    harmonic_kernel<<<n_rows, 256, 0, stream>>>(x, uwp, dwp, out);
}

// Round 2
// 220.548 us; speedup vs baseline: 1.0143x; 1.0143x over previous
//
#include <hip/hip_runtime.h>

// HarmonicMixing closed form per row of D=1024 channels (all gathers read the
// ORIGINAL x):
//   out[j] = x[j]
//          + sum_{o=1..3, s=2^o} ( [j%s==0] * sig(uw[o]) * x[j/s]        (up)
//                                 + [1<=j<D/s] * sig(dw[o]) * W_s[j] )   (down)
// where W_s[j] = sum(x[j*s .. j*s+s-1]) — a hierarchy of pair sums:
//   S1[j]=x[2j]+x[2j+1], S2=pairsum(S1), S3=pairsum(S2); W_2=S1, W_4=S2, W_8=S3.
//
// Round-1 lesson: strided LDS window reads (byte stride 32/64/128 per lane)
// cost 16-32-way bank conflicts -> LDS unit was the bottleneck (1.2 TB/s eff).
// This version computes S1/S2/S3 register-side from each thread's float4
// (+1 shuffle for S3) and makes EVERY bulk LDS access stride-1 conflict-free.

constexpr int D = 1024;

__global__ __launch_bounds__(256) void harmonic_kernel(
    const float* __restrict__ x,
    const float* __restrict__ uwp,
    const float* __restrict__ dwp,
    float* __restrict__ out)
{
    __shared__ float rowlo[512];  // x[0..511] — only half the row is ever gathered by up-terms
    __shared__ float S1[512];
    __shared__ float S2[256];
    __shared__ float S3[128];

    const int t = threadIdx.x;
    const long long base = (long long)blockIdx.x * D;

    const float uw0 = 1.f / (1.f + __expf(-uwp[0]));
    const float uw1 = 1.f / (1.f + __expf(-uwp[1]));
    const float uw2 = 1.f / (1.f + __expf(-uwp[2]));
    const float dw0 = 1.f / (1.f + __expf(-dwp[0]));
    const float dw1 = 1.f / (1.f + __expf(-dwp[1]));
    const float dw2 = 1.f / (1.f + __expf(-dwp[2]));

    const int j0 = t * 4;  // this thread's 4 consecutive channels
    const float4 v = *reinterpret_cast<const float4*>(x + base + j0);

    // register-side pair-sum hierarchy
    const float s1a = v.x + v.y;          // S1[2t]
    const float s1b = v.z + v.w;          // S1[2t+1]
    const float s2  = s1a + s1b;          // S2[t]
    const float s3  = s2 + __shfl_xor(s2, 1);  // S3[t>>1] (valid on even t)

    if (t < 128) *reinterpret_cast<float4*>(&rowlo[j0]) = v;      // stride-1 b128
    *reinterpret_cast<float2*>(&S1[2 * t]) = make_float2(s1a, s1b); // b64, 4-way alias (cheap)
    S2[t] = s2;                                                    // stride-1 b32
    if ((t & 1) == 0) S3[t >> 1] = s3;                             // 32 lanes -> 32 banks, free
    __syncthreads();

    float4 r = v;

    // --- up: out[j] += uw_o * x[j >> o] for j % 2^o == 0 ---
    const float2 u01 = *reinterpret_cast<const float2*>(&rowlo[2 * t]); // x[j0/2], x[j0/2+1]
    r.x += uw0 * u01.x;
    r.z += uw0 * u01.y;
    r.x += uw1 * rowlo[t];                       // x[j0/4]
    if ((t & 1) == 0) r.x += uw2 * rowlo[t >> 1]; // x[j0/8]

    // --- down: out[j] += dw_o * S_o[j], 1 <= j < D/2^o --- (all stride-1 b128)
    if (t < 128) {
        const float4 a = *reinterpret_cast<const float4*>(&S1[j0]);
        if (t > 0) r.x += dw0 * a.x;  // j=0 excluded
        r.y += dw0 * a.y;
        r.z += dw0 * a.z;
        r.w += dw0 * a.w;
        if (t < 64) {
            const float4 b = *reinterpret_cast<const float4*>(&S2[j0]);
            if (t > 0) r.x += dw1 * b.x;
            r.y += dw1 * b.y;
            r.z += dw1 * b.z;
            r.w += dw1 * b.w;
            if (t < 32) {
                const float4 c = *reinterpret_cast<const float4*>(&S3[j0]);
                if (t > 0) r.x += dw2 * c.x;
                r.y += dw2 * c.y;
                r.z += dw2 * c.z;
                r.w += dw2 * c.w;
            }
        }
    }

    *reinterpret_cast<float4*>(out + base + j0) = r;
}

extern "C" void kernel_launch(void* const* d_in, const int* in_sizes, int n_in,
                              void* d_out, int out_size, void* d_ws, size_t ws_size,
                              hipStream_t stream) {
    const float* x   = (const float*)d_in[0];
    const float* uwp = (const float*)d_in[1];
    const float* dwp = (const float*)d_in[2];
    float* out = (float*)d_out;
    const int n_rows = in_sizes[0] / D;  // 8 * 4096 = 32768
    harmonic_kernel<<<n_rows, 256, 0, stream>>>(x, uwp, dwp, out);
}